// Round 1
// 145.496 us; speedup vs baseline: 1.0607x; 1.0607x over previous
//
#include <hip/hip_runtime.h>
#include <math.h>

#define BN 2
#define SN 1024
#define TN 1024
#define DS 128
#define DT 64
#define HN 64
#define LN_EPS 1e-5f

typedef float v2f __attribute__((ext_vector_type(2)));

__device__ __forceinline__ float wave_sum(float v) {
#pragma unroll
  for (int m = 32; m >= 1; m >>= 1) v += __shfl_xor(v, m, 64);
  return v;
}

__device__ __forceinline__ v2f lo2(float4 v) { v2f r = {v.x, v.y}; return r; }
__device__ __forceinline__ v2f hi2(float4 v) { v2f r = {v.z, v.w}; return r; }

// broadcast lane `l` of v to all lanes via v_readlane (VALU pipe, no LDS)
__device__ __forceinline__ float rl(float v, int l) {
  return __int_as_float(__builtin_amdgcn_readlane(__float_as_int(v), l));
}

// ---------------- Kernel 1: both adapters in one launch ----------------
__global__ __launch_bounds__(256) void k_adapters(
    const float* __restrict__ src, const float* __restrict__ tgt,
    const float* __restrict__ sW1, const float* __restrict__ sb1,
    const float* __restrict__ sg, const float* __restrict__ sbeta,
    const float* __restrict__ sW2, const float* __restrict__ sb2,
    const float* __restrict__ tW1, const float* __restrict__ tb1,
    const float* __restrict__ tg, const float* __restrict__ tbeta,
    const float* __restrict__ tW2, const float* __restrict__ tb2,
    const float* __restrict__ cW, const float* __restrict__ cb,
    float* __restrict__ s_ad, float* __restrict__ sc, float* __restrict__ sstats,
    float* __restrict__ t_ad, float* __restrict__ tc, float* __restrict__ tstats)
{
  __shared__ float xbuf[4][DS];
  __shared__ float rbuf[4][HN];
  int w = threadIdx.x >> 6, lane = threadIdx.x & 63;

  if (blockIdx.x < 512) {
    int row = blockIdx.x * 4 + w;  // 0..2047
    xbuf[w][lane]      = src[row * DS + lane];
    xbuf[w][lane + 64] = src[row * DS + 64 + lane];
    float a0 = 0.f, a1 = 0.f, a2_ = 0.f, a3 = 0.f;
#pragma unroll 8
    for (int k = 0; k < DS; k += 4) {
      a0  = fmaf(xbuf[w][k + 0], sW1[(k + 0) * HN + lane], a0);
      a1  = fmaf(xbuf[w][k + 1], sW1[(k + 1) * HN + lane], a1);
      a2_ = fmaf(xbuf[w][k + 2], sW1[(k + 2) * HN + lane], a2_);
      a3  = fmaf(xbuf[w][k + 3], sW1[(k + 3) * HN + lane], a3);
    }
    float h1 = ((a0 + a1) + (a2_ + a3)) + sb1[lane];
    float s1 = wave_sum(h1), s2 = wave_sum(h1 * h1);
    float m = s1 * (1.f / HN);
    float var = s2 * (1.f / HN) - m * m;
    float r = fmaxf(0.f, (h1 - m) * rsqrtf(var + LN_EPS) * sg[lane] + sbeta[lane]);
    rbuf[w][lane] = r;
    float b0 = 0.f, b1 = 0.f, b2 = 0.f, b3 = 0.f;
#pragma unroll 4
    for (int j = 0; j < HN; j += 4) {
      b0 = fmaf(rbuf[w][j + 0], sW2[(j + 0) * HN + lane], b0);
      b1 = fmaf(rbuf[w][j + 1], sW2[(j + 1) * HN + lane], b1);
      b2 = fmaf(rbuf[w][j + 2], sW2[(j + 2) * HN + lane], b2);
      b3 = fmaf(rbuf[w][j + 3], sW2[(j + 3) * HN + lane], b3);
    }
    float a2 = ((b0 + b1) + (b2 + b3)) + sb2[lane];
    s_ad[row * HN + lane] = a2;
    rbuf[w][lane] = a2;
    float c0 = 0.f, c1 = 0.f, c2 = 0.f, c3 = 0.f;
#pragma unroll 4
    for (int j = 0; j < HN; j += 4) {
      c0 = fmaf(rbuf[w][j + 0], cW[(HN + j + 0) * HN + lane], c0);
      c1 = fmaf(rbuf[w][j + 1], cW[(HN + j + 1) * HN + lane], c1);
      c2 = fmaf(rbuf[w][j + 2], cW[(HN + j + 2) * HN + lane], c2);
      c3 = fmaf(rbuf[w][j + 3], cW[(HN + j + 3) * HN + lane], c3);
    }
    float scv = (c0 + c1) + (c2 + c3);
    sc[row * HN + lane] = scv;
    float bs = wave_sum(scv), qs = wave_sum(scv * scv);
    if (lane == 0) { sstats[row * 2] = bs; sstats[row * 2 + 1] = qs; }
  } else {
    int row = (blockIdx.x - 512) * 4 + w;  // 0..2047
    xbuf[w][lane] = tgt[row * DT + lane];
    float a0 = 0.f, a1 = 0.f, a2_ = 0.f, a3 = 0.f;
#pragma unroll 4
    for (int k = 0; k < DT; k += 4) {
      a0  = fmaf(xbuf[w][k + 0], tW1[(k + 0) * HN + lane], a0);
      a1  = fmaf(xbuf[w][k + 1], tW1[(k + 1) * HN + lane], a1);
      a2_ = fmaf(xbuf[w][k + 2], tW1[(k + 2) * HN + lane], a2_);
      a3  = fmaf(xbuf[w][k + 3], tW1[(k + 3) * HN + lane], a3);
    }
    float h1 = ((a0 + a1) + (a2_ + a3)) + tb1[lane];
    float s1 = wave_sum(h1), s2 = wave_sum(h1 * h1);
    float m = s1 * (1.f / HN);
    float var = s2 * (1.f / HN) - m * m;
    float r = fmaxf(0.f, (h1 - m) * rsqrtf(var + LN_EPS) * tg[lane] + tbeta[lane]);
    rbuf[w][lane] = r;
    float b0 = 0.f, b1 = 0.f, b2 = 0.f, b3 = 0.f;
#pragma unroll 4
    for (int j = 0; j < HN; j += 4) {
      b0 = fmaf(rbuf[w][j + 0], tW2[(j + 0) * HN + lane], b0);
      b1 = fmaf(rbuf[w][j + 1], tW2[(j + 1) * HN + lane], b1);
      b2 = fmaf(rbuf[w][j + 2], tW2[(j + 2) * HN + lane], b2);
      b3 = fmaf(rbuf[w][j + 3], tW2[(j + 3) * HN + lane], b3);
    }
    float a2 = ((b0 + b1) + (b2 + b3)) + tb2[lane];
    t_ad[row * HN + lane] = a2;
    float asum = wave_sum(a2);
    float gate = 1.f / (1.f + __expf(-asum * (1.f / HN)));
    rbuf[w][lane] = a2;
    float c0 = 0.f, c1 = 0.f, c2 = 0.f, c3 = 0.f;
#pragma unroll 4
    for (int j = 0; j < HN; j += 4) {
      c0 = fmaf(rbuf[w][j + 0], cW[(j + 0) * HN + lane], c0);
      c1 = fmaf(rbuf[w][j + 1], cW[(j + 1) * HN + lane], c1);
      c2 = fmaf(rbuf[w][j + 2], cW[(j + 2) * HN + lane], c2);
      c3 = fmaf(rbuf[w][j + 3], cW[(j + 3) * HN + lane], c3);
    }
    float tcv = ((c0 + c1) + (c2 + c3)) + cb[lane];
    tc[row * HN + lane] = tcv;
    float A = wave_sum(tcv), Q = wave_sum(tcv * tcv);
    if (lane == 0) { tstats[row * 3] = A; tstats[row * 3 + 1] = Q; tstats[row * 3 + 2] = gate; }
  }
}

// ---------------- Kernel 2: scores v9 (unchanged) ----------------
#define ROWDW 68
__global__ __launch_bounds__(512) void k_scores(
    const float* __restrict__ cg, const float* __restrict__ cbeta,
    const float* __restrict__ simW, const float* __restrict__ simb,
    const float* __restrict__ sc, const float* __restrict__ sstats,
    const float* __restrict__ tc, const float* __restrict__ tstats,
    float* __restrict__ out_scores)
{
  __shared__ float tile[64 * ROWDW];   // 17.4 KB
  int tid = threadIdx.x;
  int w = tid >> 6, lane = tid & 63;
  int sblk = blockIdx.x & 15;                // 16 s-chunks of 64
  int tblk = (blockIdx.x >> 4) & 63;         // 64 t-blocks of 16
  int b    = blockIdx.x >> 10;
  int t0 = tblk * 16 + w * 2;
  int rt0 = __builtin_amdgcn_readfirstlane(b * TN + t0);
  int rt1 = rt0 + 1;
  int s0 = sblk * 64;

  float A0  = tstats[rt0 * 3 + 0];
  float Qt0 = tstats[rt0 * 3 + 1];
  float A1  = tstats[rt1 * 3 + 0];
  float Qt1 = tstats[rt1 * 3 + 1];
  const float4* tq0 = (const float4*)(tc + rt0 * HN);  // wave-uniform
  const float4* tq1 = (const float4*)(tc + rt1 * HN);
  const float4* cgq = (const float4*)cg;
  const float4* cbq = (const float4*)cbeta;
  const float4* swq = (const float4*)simW;
  float simb0 = simb[0];

  const float4* scg = (const float4*)(sc + b * SN * HN);

  // stage 64 rows x 16 float4: 1024 cells, 2 per thread
  {
    int r0s = tid >> 4, gs = tid & 15;        // rows 0..31
    float4 v0 = scg[(s0 + r0s) * 16 + gs];
    float4 v1 = scg[(s0 + r0s + 32) * 16 + gs];
    *(float4*)&tile[r0s * ROWDW + gs * 4] = v0;
    *(float4*)&tile[(r0s + 32) * ROWDW + gs * 4] = v1;
  }
  __syncthreads();

  const v2f zero2 = {0.f, 0.f};
  const float* tb_ = &tile[lane * ROWDW];
  int s = s0 + lane;
  float2 bq = *(const float2*)&sstats[(b * SN + s) * 2];

  // pass 1 for both t: D = sum_h tc_h * sc_h (16 immediate-offset b128)
  v2f D0a = zero2, D0b = zero2, D1a = zero2, D1b = zero2;
#pragma unroll
  for (int g = 0; g < 16; ++g) {
    float4 v = *(const float4*)&tb_[g * 4];
    float4 ta = tq0[g]; float4 tbv = tq1[g];
    D0a = __builtin_elementwise_fma(lo2(ta),  lo2(v), D0a);
    D0b = __builtin_elementwise_fma(hi2(ta),  hi2(v), D0b);
    D1a = __builtin_elementwise_fma(lo2(tbv), lo2(v), D1a);
    D1b = __builtin_elementwise_fma(hi2(tbv), hi2(v), D1b);
  }
  v2f Ds0 = D0a + D0b, Ds1 = D1a + D1b;
  float D_0 = Ds0.x + Ds0.y;
  float D_1 = Ds1.x + Ds1.y;

  float mean0  = (A0 + bq.x) * (1.f / HN);
  float var0   = (Qt0 + bq.y + 2.f * D_0) * (1.f / HN) - mean0 * mean0;
  float alpha0 = rsqrtf(var0 + LN_EPS);
  float mean1  = (A1 + bq.x) * (1.f / HN);
  float var1   = (Qt1 + bq.y + 2.f * D_1) * (1.f / HN) - mean1 * mean1;
  float alpha1 = rsqrtf(var1 + LN_EPS);

  v2f m0 = {mean0, mean0}, a0v = {alpha0, alpha0};
  v2f m1 = {mean1, mean1}, a1v = {alpha1, alpha1};
  v2f dt0a = zero2, dt0b = zero2, dt1a = zero2, dt1b = zero2;

  // pass 2 for both t
#pragma unroll
  for (int g = 0; g < 16; ++g) {
    float4 v  = *(const float4*)&tb_[g * 4];
    float4 c4 = cgq[g]; float4 b4 = cbq[g]; float4 w4 = swq[g];
    float4 ta = tq0[g]; float4 tbv = tq1[g];
    { v2f u = lo2(v) + lo2(ta);  v2f z = u - m0; v2f P = a0v * lo2(c4);
      v2f n = __builtin_elementwise_fma(z, P, lo2(b4));
      v2f r = __builtin_elementwise_max(n, zero2);
      dt0a = __builtin_elementwise_fma(r, lo2(w4), dt0a); }
    { v2f u = hi2(v) + hi2(ta);  v2f z = u - m0; v2f P = a0v * hi2(c4);
      v2f n = __builtin_elementwise_fma(z, P, hi2(b4));
      v2f r = __builtin_elementwise_max(n, zero2);
      dt0b = __builtin_elementwise_fma(r, hi2(w4), dt0b); }
    { v2f u = lo2(v) + lo2(tbv); v2f z = u - m1; v2f P = a1v * lo2(c4);
      v2f n = __builtin_elementwise_fma(z, P, lo2(b4));
      v2f r = __builtin_elementwise_max(n, zero2);
      dt1a = __builtin_elementwise_fma(r, lo2(w4), dt1a); }
    { v2f u = hi2(v) + hi2(tbv); v2f z = u - m1; v2f P = a1v * hi2(c4);
      v2f n = __builtin_elementwise_fma(z, P, hi2(b4));
      v2f r = __builtin_elementwise_max(n, zero2);
      dt1b = __builtin_elementwise_fma(r, hi2(w4), dt1b); }
  }
  v2f dd0 = dt0a + dt0b, dd1 = dt1a + dt1b;
  float dot0 = dd0.x + dd0.y;
  float dot1 = dd1.x + dd1.y;
  float score0 = 1.f / (1.f + __expf(-(dot0 + simb0)));
  float score1 = 1.f / (1.f + __expf(-(dot1 + simb0)));
  out_scores[rt0 * SN + s] = score0;
  out_scores[rt1 * SN + s] = score1;
}

// ---------------- Kernel 3: fused transfer + softmax + gate ----------------
// Replaces k_xfer + k_final. 512 blocks x 4 waves; block owns 4 t-rows x all
// 1024 s (each wave a contiguous 256-s span). e-broadcast via v_readlane
// (VALU pipe) instead of 256 ds_read_b128 LDS broadcasts per wave; softmax
// denominator held in registers; single barrier for the 4-wave part-reduce.
// No xpart/epart HBM round-trip, no separate final kernel.
__global__ __launch_bounds__(256) void k_transfer(
    const float* __restrict__ scores, const float* __restrict__ s_ad,
    const float* __restrict__ t_ad, const float* __restrict__ tstats,
    float* __restrict__ out_adapted)
{
  __shared__ float part[4][4][64];   // [wave][t][h]  4 KB
  __shared__ float esumLDS[4][4];    // [wave][t]
  int tid = threadIdx.x;
  int w = tid >> 6, lane = tid & 63;
  int tblk = blockIdx.x & 255;       // 256 t-blocks of 4
  int b    = blockIdx.x >> 8;
  int rtb  = b * TN + tblk * 4;
  const float* sadb = s_ad + b * SN * HN;

  float acc0 = 0.f, acc1 = 0.f, acc2 = 0.f, acc3 = 0.f;
  float es0 = 0.f, es1 = 0.f, es2 = 0.f, es3 = 0.f;
  int s0w = w * 256;                 // this wave's s-span

#pragma unroll
  for (int sub = 0; sub < 4; ++sub) {
    int sbase = s0w + sub * 64;
    // e-phase: lane = s; one coalesced 256B load + one v_exp per t-row
    float e0 = __expf(scores[(rtb + 0) * SN + sbase + lane]);
    float e1 = __expf(scores[(rtb + 1) * SN + sbase + lane]);
    float e2 = __expf(scores[(rtb + 2) * SN + sbase + lane]);
    float e3 = __expf(scores[(rtb + 3) * SN + sbase + lane]);
    es0 += e0; es1 += e1; es2 += e2; es3 += e3;
    // acc-phase: lane = h; e[t][si] fetched cross-lane via readlane
    const float* srow = sadb + sbase * HN + lane;
#pragma unroll 16
    for (int si = 0; si < 64; ++si) {
      float sv = srow[si * HN];
      acc0 = fmaf(rl(e0, si), sv, acc0);
      acc1 = fmaf(rl(e1, si), sv, acc1);
      acc2 = fmaf(rl(e2, si), sv, acc2);
      acc3 = fmaf(rl(e3, si), sv, acc3);
    }
  }

  part[w][0][lane] = acc0;
  part[w][1][lane] = acc1;
  part[w][2][lane] = acc2;
  part[w][3][lane] = acc3;
  float t0s = wave_sum(es0), t1s = wave_sum(es1);
  float t2s = wave_sum(es2), t3s = wave_sum(es3);
  if (lane == 0) {
    esumLDS[w][0] = t0s; esumLDS[w][1] = t1s;
    esumLDS[w][2] = t2s; esumLDS[w][3] = t3s;
  }
  __syncthreads();

  // combine: 256 threads = 4t x 64h, one cell each
  int t = w, h = lane;
  float x  = part[0][t][h] + part[1][t][h] + part[2][t][h] + part[3][t][h];
  float es = esumLDS[0][t] + esumLDS[1][t] + esumLDS[2][t] + esumLDS[3][t];
  int rt = rtb + t;
  float tr = x / es;
  float gate = tstats[rt * 3 + 2];
  float tad = t_ad[rt * HN + h];
  out_adapted[rt * HN + h] = tad * (1.f - gate) + tr * gate;
}

extern "C" void kernel_launch(void* const* d_in, const int* in_sizes, int n_in,
                              void* d_out, int out_size, void* d_ws, size_t ws_size,
                              hipStream_t stream) {
  const float* src   = (const float*)d_in[0];
  const float* tgt   = (const float*)d_in[1];
  const float* sW1   = (const float*)d_in[2];
  const float* sb1   = (const float*)d_in[3];
  const float* sg    = (const float*)d_in[4];
  const float* sbeta = (const float*)d_in[5];
  const float* sW2   = (const float*)d_in[6];
  const float* sb2   = (const float*)d_in[7];
  const float* tW1   = (const float*)d_in[8];
  const float* tb1   = (const float*)d_in[9];
  const float* tg    = (const float*)d_in[10];
  const float* tbeta = (const float*)d_in[11];
  const float* tW2   = (const float*)d_in[12];
  const float* tb2   = (const float*)d_in[13];
  const float* cW    = (const float*)d_in[14];
  const float* cb    = (const float*)d_in[15];
  const float* cg    = (const float*)d_in[16];
  const float* cbeta = (const float*)d_in[17];
  const float* simW  = (const float*)d_in[18];
  const float* simb  = (const float*)d_in[19];

  float* ws     = (float*)d_ws;
  float* s_ad   = ws;               // 131072
  float* sc     = ws + 131072;      // 131072
  float* sstats = ws + 262144;      // 4096
  float* t_ad   = ws + 266240;      // 131072
  float* tc     = ws + 397312;      // 131072
  float* tstats = ws + 528384;      // 6144

  float* out_adapted = (float*)d_out;            // B*T*H
  float* out_scores  = (float*)d_out + 131072;   // B*T*S

  hipLaunchKernelGGL(k_adapters, dim3(1024), dim3(256), 0, stream,
                     src, tgt, sW1, sb1, sg, sbeta, sW2, sb2,
                     tW1, tb1, tg, tbeta, tW2, tb2, cW, cb,
                     s_ad, sc, sstats, t_ad, tc, tstats);
  hipLaunchKernelGGL(k_scores, dim3(BN * 64 * 16), dim3(512), 0, stream,
                     cg, cbeta, simW, simb, sc, sstats, tc, tstats, out_scores);
  hipLaunchKernelGGL(k_transfer, dim3(BN * 256), dim3(256), 0, stream,
                     out_scores, s_ad, t_ad, tstats, out_adapted);
}